// Round 1
// baseline (310.735 us; speedup 1.0000x reference)
//
#include <hip/hip_runtime.h>
#include <hip/hip_bf16.h>
#include <cstdint>
#include <cstddef>

#define N_TOK 8192
#define D_IN  1024
#define D_OUT 1024
#define N_EXP 8
#define KTOT  (N_EXP * D_IN)   // 8192

typedef __attribute__((ext_vector_type(8))) short short8;
typedef __attribute__((ext_vector_type(8))) unsigned short ushort8;
typedef __attribute__((ext_vector_type(4))) float f32x4;

// RNE float->bf16 (inputs are finite; no NaN handling needed)
__device__ __forceinline__ unsigned short f2bf(float f) {
    union { float f; unsigned int u; } v; v.f = f;
    return (unsigned short)((v.u + 0x7FFFu + ((v.u >> 16) & 1u)) >> 16);
}

__device__ __forceinline__ void load_lds16(const void* g, void* l) {
    __builtin_amdgcn_global_load_lds(
        (const __attribute__((address_space(1))) void*)g,
        (__attribute__((address_space(3))) void*)l,
        16, 0, 0);
}

// ---------------------------------------------------------------------------
// Kernel 1: fused gate (softmax(x@gate_W + gate_b)) + x fp32->bf16 convert.
// One block per token. g written transposed: g_t[e][n].
// ---------------------------------------------------------------------------
__global__ __launch_bounds__(256) void gate_xconv_kernel(
    const float* __restrict__ x, const float* __restrict__ gW,
    const float* __restrict__ gb, unsigned short* __restrict__ xb,
    float* __restrict__ g_t) {
    const int n = blockIdx.x;
    const int t = threadIdx.x;

    const float4 xv = *(const float4*)(x + (size_t)n * D_IN + 4 * t);

    // bf16 convert + packed 8B store
    ushort4 u;
    u.x = f2bf(xv.x); u.y = f2bf(xv.y); u.z = f2bf(xv.z); u.w = f2bf(xv.w);
    *(ushort4*)(xb + (size_t)n * D_IN + 4 * t) = u;

    // partial gate dots: this thread covers i = 4t..4t+3
    float acc[8];
#pragma unroll
    for (int e = 0; e < 8; ++e) acc[e] = 0.f;
    const float xs[4] = {xv.x, xv.y, xv.z, xv.w};
#pragma unroll
    for (int j = 0; j < 4; ++j) {
        const float* wr = gW + (size_t)(4 * t + j) * N_EXP;  // row of gate_W, 8 floats
        const float4 w0 = *(const float4*)wr;
        const float4 w1 = *(const float4*)(wr + 4);
        acc[0] += xs[j] * w0.x; acc[1] += xs[j] * w0.y;
        acc[2] += xs[j] * w0.z; acc[3] += xs[j] * w0.w;
        acc[4] += xs[j] * w1.x; acc[5] += xs[j] * w1.y;
        acc[6] += xs[j] * w1.z; acc[7] += xs[j] * w1.w;
    }
    // wave (64-lane) reduce
#pragma unroll
    for (int off = 32; off > 0; off >>= 1) {
#pragma unroll
        for (int e = 0; e < 8; ++e) acc[e] += __shfl_down(acc[e], off);
    }
    __shared__ float red[4][8];
    if ((t & 63) == 0) {
#pragma unroll
        for (int e = 0; e < 8; ++e) red[t >> 6][e] = acc[e];
    }
    __syncthreads();
    if (t == 0) {
        float lg[8], mx = -1e30f;
#pragma unroll
        for (int e = 0; e < 8; ++e) {
            lg[e] = red[0][e] + red[1][e] + red[2][e] + red[3][e] + gb[e];
            mx = fmaxf(mx, lg[e]);
        }
        float s = 0.f;
#pragma unroll
        for (int e = 0; e < 8; ++e) { lg[e] = expf(lg[e] - mx); s += lg[e]; }
        const float inv = 1.f / s;
#pragma unroll
        for (int e = 0; e < 8; ++e) g_t[(size_t)e * N_TOK + n] = lg[e] * inv;
    }
}

// ---------------------------------------------------------------------------
// Kernel 2: W [e][i][o] fp32 -> W_t [o][e*1024+i] bf16 (transpose + convert).
// 64x64 LDS-tiled transpose per (o-tile, i-tile, e).
// ---------------------------------------------------------------------------
__global__ __launch_bounds__(256) void wconv_kernel(
    const float* __restrict__ W, unsigned short* __restrict__ Wt) {
    __shared__ float tile[64][65];  // +1 pad breaks transpose-read conflicts
    const int e  = blockIdx.z;
    const int i0 = blockIdx.y * 64;
    const int o0 = blockIdx.x * 64;
    const int t  = threadIdx.x;
    const int r  = t >> 2;          // 0..63
    const int c  = (t & 3) * 16;    // 0,16,32,48

    const float* src = W + ((size_t)e * D_IN + (i0 + r)) * D_OUT + o0 + c;
#pragma unroll
    for (int j = 0; j < 4; ++j) {
        const float4 v = *(const float4*)(src + 4 * j);
        tile[r][c + 4 * j + 0] = v.x;
        tile[r][c + 4 * j + 1] = v.y;
        tile[r][c + 4 * j + 2] = v.z;
        tile[r][c + 4 * j + 3] = v.w;
    }
    __syncthreads();
    // write row o = o0+r of W_t, k-chunk e*1024 + i0 + c .. +15
    ushort8 v0, v1;
#pragma unroll
    for (int j = 0; j < 8; ++j) v0[j] = f2bf(tile[c + j][r]);
#pragma unroll
    for (int j = 0; j < 8; ++j) v1[j] = f2bf(tile[c + 8 + j][r]);
    unsigned short* dst = Wt + (size_t)(o0 + r) * KTOT + e * D_IN + i0 + c;
    *(ushort8*)dst = v0;
    *(ushort8*)(dst + 8) = v1;
}

// ---------------------------------------------------------------------------
// Kernel 3: main GEMM. out[n][o] = sum_e g[n][e]*( x[n][:]@W_e[:,o] + b[e][o] )
// 128x128 tile, BK=32, 16x16x32 bf16 MFMA, global_load_lds width=16 staging.
// Per-expert accumulator initialized to bias, rescaled by g at expert boundary.
// ---------------------------------------------------------------------------
__global__ __launch_bounds__(256, 2) void moe_gemm_kernel(
    const unsigned short* __restrict__ xb,   // [N_TOK][D_IN] bf16
    const unsigned short* __restrict__ Wt,   // [D_OUT][KTOT] bf16
    const float* __restrict__ bias,          // [N_EXP][D_OUT]
    const float* __restrict__ g_t,           // [N_EXP][N_TOK]
    float* __restrict__ out) {               // [N_TOK][D_OUT]
    __shared__ __align__(16) unsigned short Abuf[128 * 32];  // [m][k]
    __shared__ __align__(16) unsigned short Bbuf[128 * 32];  // [n][k]
    __shared__ __align__(16) float g_s[N_EXP][128];
    __shared__ __align__(16) float b_s[N_EXP][128];

    const int t    = threadIdx.x;
    const int lane = t & 63;
    const int ln15 = lane & 15;
    const int quad = lane >> 4;
    const int wave = t >> 6;
    const int wm0  = (wave >> 1) * 64;
    const int wn0  = (wave & 1) * 64;
    const int bm0  = blockIdx.y * 128;
    const int bn0  = blockIdx.x * 128;

    // stage gate block [8][128 rows] and bias block [8][128 cols]
    for (int j = t; j < N_EXP * 128; j += 256) {
        const int e = j >> 7, r = j & 127;
        g_s[e][r] = g_t[(size_t)e * N_TOK + bm0 + r];
        b_s[e][r] = bias[(size_t)e * D_OUT + bn0 + r];
    }

    f32x4 accF[4][4];
#pragma unroll
    for (int mi = 0; mi < 4; ++mi)
#pragma unroll
        for (int ni = 0; ni < 4; ++ni)
            accF[mi][ni] = (f32x4){0.f, 0.f, 0.f, 0.f};

    // wave-uniform LDS staging bases (HW adds lane*16)
    unsigned short* aLds0 = &Abuf[wave * 512];
    unsigned short* aLds1 = &Abuf[2048 + wave * 512];
    unsigned short* bLds0 = &Bbuf[wave * 512];
    unsigned short* bLds1 = &Bbuf[2048 + wave * 512];

    // per-thread global staging bases: row = base + t/4, k-chunk = (t&3)*8
    const unsigned short* gaBase =
        xb + (size_t)(bm0 + (t >> 2)) * D_IN + (t & 3) * 8;
    const unsigned short* gbBase =
        Wt + (size_t)(bn0 + (t >> 2)) * KTOT + (t & 3) * 8;

    __syncthreads();  // g_s / b_s ready

    for (int e = 0; e < N_EXP; ++e) {
        float bval[4];
#pragma unroll
        for (int ni = 0; ni < 4; ++ni) bval[ni] = b_s[e][wn0 + ni * 16 + ln15];
        f32x4 acc[4][4];
#pragma unroll
        for (int mi = 0; mi < 4; ++mi)
#pragma unroll
            for (int ni = 0; ni < 4; ++ni)
                acc[mi][ni] = (f32x4){bval[ni], bval[ni], bval[ni], bval[ni]};

        const unsigned short* ga = gaBase;                 // x cols 0..1023
        const unsigned short* gb = gbBase + e * D_IN;      // W_t cols e*1024..

        for (int kk = 0; kk < 32; ++kk) {
            __syncthreads();  // prior MFMA LDS reads done before overwrite
            load_lds16(ga + kk * 32,               aLds0);
            load_lds16(ga + 64 * D_IN + kk * 32,   aLds1);
            load_lds16(gb + kk * 32,               bLds0);
            load_lds16(gb + 64 * KTOT + kk * 32,   bLds1);
            __syncthreads();  // tiles visible

            short8 af[4], bv[4];
#pragma unroll
            for (int mi = 0; mi < 4; ++mi)
                af[mi] = *(const short8*)&Abuf[(wm0 + mi * 16 + ln15) * 32 + quad * 8];
#pragma unroll
            for (int ni = 0; ni < 4; ++ni)
                bv[ni] = *(const short8*)&Bbuf[(wn0 + ni * 16 + ln15) * 32 + quad * 8];
#pragma unroll
            for (int mi = 0; mi < 4; ++mi)
#pragma unroll
                for (int ni = 0; ni < 4; ++ni)
                    acc[mi][ni] = __builtin_amdgcn_mfma_f32_16x16x32_bf16(
                        af[mi], bv[ni], acc[mi][ni], 0, 0, 0);
        }

        // expert boundary: accF += g[row,e] * acc   (rows quad*4+r contiguous)
#pragma unroll
        for (int mi = 0; mi < 4; ++mi) {
            const f32x4 gv = *(const f32x4*)&g_s[e][wm0 + mi * 16 + quad * 4];
#pragma unroll
            for (int ni = 0; ni < 4; ++ni) {
#pragma unroll
                for (int r = 0; r < 4; ++r)
                    accF[mi][ni][r] += gv[r] * acc[mi][ni][r];
            }
        }
    }

    // epilogue: C layout col=lane&15, row=quad*4+reg
#pragma unroll
    for (int mi = 0; mi < 4; ++mi) {
#pragma unroll
        for (int ni = 0; ni < 4; ++ni) {
            const int col  = bn0 + wn0 + ni * 16 + ln15;
            const int row0 = bm0 + wm0 + mi * 16 + quad * 4;
#pragma unroll
            for (int r = 0; r < 4; ++r)
                out[(size_t)(row0 + r) * D_OUT + col] = accF[mi][ni][r];
        }
    }
}

// ---------------------------------------------------------------------------
extern "C" void kernel_launch(void* const* d_in, const int* in_sizes, int n_in,
                              void* d_out, int out_size, void* d_ws, size_t ws_size,
                              hipStream_t stream) {
    const float* x  = (const float*)d_in[0];
    const float* W  = (const float*)d_in[1];
    const float* b  = (const float*)d_in[2];
    const float* gW = (const float*)d_in[3];
    const float* gb = (const float*)d_in[4];
    float* out = (float*)d_out;

    // workspace layout: x_bf16 (16MB) | W_t bf16 (16MB) | g_t fp32 (256KB)
    unsigned short* xb  = (unsigned short*)d_ws;
    unsigned short* Wt  = xb + (size_t)N_TOK * D_IN;
    float*          g_t = (float*)(Wt + (size_t)D_OUT * KTOT);

    gate_xconv_kernel<<<N_TOK, 256, 0, stream>>>(x, gW, gb, xb, g_t);
    wconv_kernel<<<dim3(16, 16, 8), 256, 0, stream>>>(W, Wt);
    moe_gemm_kernel<<<dim3(D_OUT / 128, N_TOK / 128), 256, 0, stream>>>(
        xb, Wt, b, g_t, out);
}